// Round 17
// baseline (147.696 us; speedup 1.0000x reference)
//
#include <hip/hip_runtime.h>
#include <hip/hip_bf16.h>

typedef _Float16 half8v __attribute__((ext_vector_type(8)));
typedef _Float16 half4v __attribute__((ext_vector_type(4)));
typedef _Float16 half2v __attribute__((ext_vector_type(2)));
typedef __fp16   fp16x2 __attribute__((ext_vector_type(2)));
typedef __attribute__((ext_vector_type(4))) float floatx4;

#define LOG2E_OVER_8 0.18033688011112042f

// ===== Frag-order layouts (verified r9-r16) =================================
// Kh chunk(t16,c): ((t16*2+c)*64 + quad*16 + m)*8 halves  (A-frag 16x16x32)
// Qh: same with m=q%16. Vh chunk(t64,dt,ktp): (((t64*8)+dt*2+ktp)*64+quad*16+m)*8
// Wt: ((ctg*16+kc)*64 + quad*16 + m)*8
// => every frag load = 64 lanes x contiguous 16B = 1 KB coalesced global read.
// x (row-major fp32) is ALSO frag-loadable directly: lane(m,quad) reads
// x[row0+m][kc*32+quad*8..+8] -> 16 contiguous 128B segments per instruction.

// ---------------- Kernel 0: W -> frag-order Wt fp16 -------------------------
__global__ __launch_bounds__(256) void wtrans_k(const float* __restrict__ Wq,
                                                const float* __restrict__ Wk,
                                                const float* __restrict__ Wv,
                                                _Float16* __restrict__ Wt) {
    int idx = blockIdx.x * 256 + threadIdx.x;   // 98304 = 3*512*64
    int p = idx >> 15, rem = idx & 32767;
    int k = rem >> 6;      // input row
    int n = rem & 63;      // input col (lane-fast -> coalesced read)
    const float* W = (p == 0) ? Wq : ((p == 1) ? Wk : Wv);
    int ctg = p * 4 + (n >> 4), m = n & 15;
    int kc = k >> 5, quad = (k >> 3) & 3, j = k & 7;
    Wt[(((ctg << 4) + kc) * 64 + (quad << 4) + m) * 8 + j] = (_Float16)W[k * 64 + n];
}

// ---------------- Kernel 1: QKV projection, LDS-free, 32-row W reuse --------
// grid 512 x 256 (4 waves). Block = 32 rows; wave = 3 N-tiles over both
// 16-row tiles. x read DIRECTLY as A-frags (coalesced 128B segments, no LDS,
// no barrier, no staging VALU); each W-chunk load feeds 2 MFMAs.
__global__ __launch_bounds__(256) void proj_k(const float* __restrict__ x,
                                              const _Float16* __restrict__ Wt,
                                              const float* __restrict__ bq,
                                              const float* __restrict__ bk,
                                              const float* __restrict__ bv,
                                              _Float16* __restrict__ Qh,
                                              _Float16* __restrict__ Kh,
                                              _Float16* __restrict__ Vh) {
    int tid = threadIdx.x, l = tid & 63, wv = tid >> 6;
    int m = l & 15, quad = l >> 4;
    int row0 = blockIdx.x * 32;

    const float* xr0 = x + (row0 + m) * 512 + quad * 8;
    const float* xr1 = x + (row0 + 16 + m) * 512 + quad * 8;

    floatx4 acc[2][3];
#pragma unroll
    for (int s = 0; s < 2; s++)
#pragma unroll
        for (int i = 0; i < 3; i++) acc[s][i] = (floatx4)(0.f);

#pragma unroll 4
    for (int kc = 0; kc < 16; kc++) {
        float4 a0a = *(const float4*)(xr0 + kc * 32);
        float4 a0b = *(const float4*)(xr0 + kc * 32 + 4);
        float4 a1a = *(const float4*)(xr1 + kc * 32);
        float4 a1b = *(const float4*)(xr1 + kc * 32 + 4);
        union { _Float16 h[8]; half8v v; } A0, A1;
        A0.h[0] = (_Float16)a0a.x; A0.h[1] = (_Float16)a0a.y;
        A0.h[2] = (_Float16)a0a.z; A0.h[3] = (_Float16)a0a.w;
        A0.h[4] = (_Float16)a0b.x; A0.h[5] = (_Float16)a0b.y;
        A0.h[6] = (_Float16)a0b.z; A0.h[7] = (_Float16)a0b.w;
        A1.h[0] = (_Float16)a1a.x; A1.h[1] = (_Float16)a1a.y;
        A1.h[2] = (_Float16)a1a.z; A1.h[3] = (_Float16)a1a.w;
        A1.h[4] = (_Float16)a1b.x; A1.h[5] = (_Float16)a1b.y;
        A1.h[6] = (_Float16)a1b.z; A1.h[7] = (_Float16)a1b.w;
#pragma unroll
        for (int ct = 0; ct < 3; ct++) {
            int ctg = wv * 3 + ct;
            half8v b = *(const half8v*)(Wt + (((ctg << 4) + kc) * 64 + l) * 8);
            acc[0][ct] = __builtin_amdgcn_mfma_f32_16x16x32_f16(A0.v, b, acc[0][ct], 0, 0, 0);
            acc[1][ct] = __builtin_amdgcn_mfma_f32_16x16x32_f16(A1.v, b, acc[1][ct], 0, 0, 0);
        }
    }

#pragma unroll
    for (int s = 0; s < 2; s++) {
        int rowb = row0 + s * 16;
#pragma unroll
        for (int ct = 0; ct < 3; ct++) {
            int ctg = wv * 3 + ct;
            int col = ctg * 16 + m;
            float bias = (ctg < 4) ? bq[col] : ((ctg < 8) ? bk[col - 64] : bv[col - 128]);
            if (ctg < 8) {
                _Float16* dst = (ctg < 4) ? Qh : Kh;
                float scl = (ctg < 4) ? LOG2E_OVER_8 : 1.0f;
                int dd = (ctg & 3) * 16 + m;
                int c = dd >> 5, quadQ = (dd >> 3) & 3, j = dd & 7;
#pragma unroll
                for (int r = 0; r < 4; r++) {
                    int row = rowb + quad * 4 + r;
                    int chunk = ((row >> 4) << 1) + c;
                    dst[(chunk * 64 + quadQ * 16 + (row & 15)) * 8 + j] =
                        (_Float16)((acc[s][ct][r] + bias) * scl);
                }
            } else {
                int dt = ctg - 8;
                int t64 = rowb >> 6, ktp = (rowb >> 5) & 1, half = (rowb >> 4) & 1;
                int chunk = t64 * 8 + dt * 2 + ktp;
                union { _Float16 h[4]; unsigned long long u; } pk;
#pragma unroll
                for (int r = 0; r < 4; r++) pk.h[r] = (_Float16)(acc[s][ct][r] + bias);
                *(unsigned long long*)(Vh + (chunk * 64 + quad * 16 + m) * 8 + half * 4) = pk.u;
            }
        }
    }
}

// ---------------- Kernel 2: attention (plateau config, verified r13/r16) ----
// grid = qblk x ngrp (ngrp = spl*4; bid & (ngrp-1) -> XCD-pinned K/V slice).
// Block: 4 independent waves (no __syncthreads), 32 q each, NT 64-key tiles.
// All frag loads 1 KB coalesced from frag-order Kh/Vh (L2-resident).
// Partial numerators written as fp16 (error ~1e-6 after division).
template <int NT>
__global__ __launch_bounds__(256) void attn_k(const _Float16* __restrict__ Qh,
                                              const _Float16* __restrict__ Kh,
                                              const _Float16* __restrict__ Vh,
                                              const int* __restrict__ mask,
                                              _Float16* __restrict__ Np,
                                              float* __restrict__ Dp,
                                              int gshift) {
    __shared__ float T[4][16 * 68];   // wave-private epilogue transpose (17.4 KB)

    int tid = threadIdx.x, l = tid & 63, wv = tid >> 6;
    int m = l & 15, quad = l >> 4;
    int bid = blockIdx.x;
    int grp = bid & ((1 << gshift) - 1), qblk = bid >> gshift;
    int os = grp >> 2, b = grp & 3;
    int q0 = qblk * 128 + wv * 32;

    const int* maskb = mask + b * 4096 + os * (NT * 64);
    int az = 0;
#pragma unroll
    for (int i = 0; i < NT; i++) az |= (maskb[l + i * 64] == 0);
    const bool hasz = __any(az);

    int qt_g = (b * 4096 + q0) >> 4;
    half8v qf[2][2];
#pragma unroll
    for (int qt = 0; qt < 2; qt++)
#pragma unroll
        for (int c = 0; c < 2; c++)
            qf[qt][c] = *(const half8v*)(Qh + (((qt_g + qt) * 2 + c) * 64 + l) * 8);

    int tb0 = (b * 64 + os * NT) * 512;   // uint4 idx of this slice's tile 0
    const uint4* kh4 = (const uint4*)Kh + tb0;
    const uint4* vh4 = (const uint4*)Vh + tb0;

    floatx4 oacc[2][4];
#pragma unroll
    for (int qt = 0; qt < 2; qt++)
#pragma unroll
        for (int dt = 0; dt < 4; dt++) oacc[qt][dt] = (floatx4)(0.f);
    float dl[2] = {0.f, 0.f};

#pragma unroll 2
    for (int t = 0; t < NT; t++) {
        const uint4* kt4 = kh4 + t * 512;
        const uint4* vt4 = vh4 + t * 512;
        uint4 vv[4];
#pragma unroll
        for (int sub = 0; sub < 4; sub++) {
            union { uint4 u; half8v h; } ku0, ku1;
            ku0.u = kt4[(sub * 2 + 0) * 64 + l];
            ku1.u = kt4[(sub * 2 + 1) * 64 + l];
            if ((sub & 1) == 0) {
#pragma unroll
                for (int dt = 0; dt < 4; dt++)
                    vv[dt] = vt4[(dt * 2 + (sub >> 1)) * 64 + l];
            }
            half4v pb[2];
#pragma unroll
            for (int qt = 0; qt < 2; qt++) {
                floatx4 sf = (floatx4)(0.f);
                sf = __builtin_amdgcn_mfma_f32_16x16x32_f16(ku0.h, qf[qt][0], sf, 0, 0, 0);
                sf = __builtin_amdgcn_mfma_f32_16x16x32_f16(ku1.h, qf[qt][1], sf, 0, 0, 0);
                float p0 = exp2f(sf[0]), p1 = exp2f(sf[1]);
                float p2 = exp2f(sf[2]), p3 = exp2f(sf[3]);
                dl[qt] += (p0 + p1) + (p2 + p3);
                if (hasz) {   // post-softmax -inf fill (rare path)
                    int kg = t * 64 + sub * 16 + quad * 4;
                    if (maskb[kg + 0] == 0) p0 = -__builtin_inff();
                    if (maskb[kg + 1] == 0) p1 = -__builtin_inff();
                    if (maskb[kg + 2] == 0) p2 = -__builtin_inff();
                    if (maskb[kg + 3] == 0) p3 = -__builtin_inff();
                }
                union { fp16x2 h[2]; half4v h4; } pu;
                pu.h[0] = __builtin_amdgcn_cvt_pkrtz(p0, p1);
                pu.h[1] = __builtin_amdgcn_cvt_pkrtz(p2, p3);
                pb[qt] = pu.h4;
            }
#pragma unroll
            for (int dt = 0; dt < 4; dt++) {
                union { uint4 u; half4v h[2]; } vc; vc.u = vv[dt];
                half4v va = vc.h[sub & 1];
                oacc[0][dt] = __builtin_amdgcn_mfma_f32_16x16x16f16(va, pb[0], oacc[0][dt], 0, 0, 0);
                oacc[1][dt] = __builtin_amdgcn_mfma_f32_16x16x16f16(va, pb[1], oacc[1][dt], 0, 0, 0);
            }
        }
    }

    // epilogue: den + O^T transpose via wave-private LDS (no barrier), fp16 out
    float* Tw = &T[wv][0];
    int rowb = os * 16384 + b * 4096 + q0;
#pragma unroll
    for (int qt = 0; qt < 2; qt++) {
        float dqt = dl[qt];
        dqt += __shfl_xor(dqt, 16, 64);
        dqt += __shfl_xor(dqt, 32, 64);
        if (l < 16) Dp[rowb + qt * 16 + l] = dqt;
#pragma unroll
        for (int dt = 0; dt < 4; dt++)
#pragma unroll
            for (int r = 0; r < 4; r++)
                Tw[m * 68 + dt * 16 + quad * 4 + r] = oacc[qt][dt][r];
        __builtin_amdgcn_s_waitcnt(0);   // wave-private LDS: lgkm drain only
#pragma unroll
        for (int g = 0; g < 4; g++) {
            int idx = g * 64 + l;
            int row = idx >> 4, c4 = (idx & 15) * 4;
            float4 v = *(const float4*)(Tw + row * 68 + c4);
            union { half4v h; unsigned long long u; } pk;
            pk.h[0] = (_Float16)v.x; pk.h[1] = (_Float16)v.y;
            pk.h[2] = (_Float16)v.z; pk.h[3] = (_Float16)v.w;
            *(unsigned long long*)(Np + (size_t)(rowb + qt * 16 + row) * 64 + c4) = pk.u;
        }
        __builtin_amdgcn_s_waitcnt(0);   // reads done before next qt overwrite
    }
}

// ---------------- Kernel 3: combine spl key-split partials (fp16 Np) --------
__global__ __launch_bounds__(256) void combine_k(const _Float16* __restrict__ Np,
                                                 const float* __restrict__ Dp,
                                                 float* __restrict__ out,
                                                 int spl) {
    int g4 = blockIdx.x * 256 + threadIdx.x;   // 262144 groups of 4 values
    int row = g4 >> 4;
    float4 nu = make_float4(0.f, 0.f, 0.f, 0.f);
    float d = 0.f;
    for (int sp = 0; sp < spl; sp++) {
        union { unsigned long long u; half4v h; } v;
        v.u = *(const unsigned long long*)(Np + ((size_t)sp << 20) + (size_t)g4 * 4);
        nu.x += (float)v.h[0]; nu.y += (float)v.h[1];
        nu.z += (float)v.h[2]; nu.w += (float)v.h[3];
        d += Dp[sp * 16384 + row];
    }
    float inv = 1.0f / d;
    ((float4*)out)[g4] = make_float4(nu.x * inv, nu.y * inv, nu.z * inv, nu.w * inv);
}

extern "C" void kernel_launch(void* const* d_in, const int* in_sizes, int n_in,
                              void* d_out, int out_size, void* d_ws, size_t ws_size,
                              hipStream_t stream) {
    const float* x  = (const float*)d_in[0];
    const int* mask = (const int*)d_in[1];
    const float* Wq = (const float*)d_in[2];
    const float* bq = (const float*)d_in[3];
    const float* Wk = (const float*)d_in[4];
    const float* bk = (const float*)d_in[5];
    const float* Wv = (const float*)d_in[6];
    const float* bv = (const float*)d_in[7];
    float* out = (float*)d_out;

    char* ws = (char*)d_ws;
    _Float16* Wt = (_Float16*)(ws);              // 192 KB frag-order
    _Float16* Qh = (_Float16*)(ws + 0x40000);    // 2 MB frag-order
    _Float16* Kh = (_Float16*)(ws + 0x240000);   // 2 MB frag-order
    _Float16* Vh = (_Float16*)(ws + 0x440000);   // 2 MB V^T frag-order
    float*    Dp = (float*)(ws + 0x640000);      // 256 KB [4][16384]
    _Float16* Np = (_Float16*)(ws + 0x740000);   // 4 * 2 MB fp16 partials

    // spl = 4: attn shown split-invariant (r10/r12/r13); combine traffic halved
    wtrans_k<<<384, 256, 0, stream>>>(Wq, Wk, Wv, Wt);
    proj_k<<<512, 256, 0, stream>>>(x, Wt, bq, bk, bv, Qh, Kh, Vh);
    attn_k<16><<<32 * 16, 256, 0, stream>>>(Qh, Kh, Vh, mask, Np, Dp, 4);
    combine_k<<<1024, 256, 0, stream>>>(Np, Dp, out, 4);
}

// Round 18
// 136.824 us; speedup vs baseline: 1.0795x; 1.0795x over previous
//
#include <hip/hip_runtime.h>
#include <hip/hip_bf16.h>

typedef _Float16 half8v __attribute__((ext_vector_type(8)));
typedef _Float16 half4v __attribute__((ext_vector_type(4)));
typedef _Float16 half2v __attribute__((ext_vector_type(2)));
typedef __fp16   fp16x2 __attribute__((ext_vector_type(2)));
typedef __attribute__((ext_vector_type(4))) float floatx4;

#define LOG2E_OVER_8 0.18033688011112042f

// ===== Frag-order layouts (verified r9-r17) =================================
// Kh chunk(t16,c): ((t16*2+c)*64 + quad*16 + m)*8 halves  (A-frag 16x16x32)
// Qh: same with m=q%16. Vh chunk(t64,dt,ktp): (((t64*8)+dt*2+ktp)*64+quad*16+m)*8
// Wt: ((ctg*16+kc)*64 + quad*16 + m)*8
// => every frag load = 64 lanes x contiguous 16B = 1 KB coalesced global read.

// ---------------- Kernel 0: W -> frag-order Wt fp16 -------------------------
__global__ __launch_bounds__(256) void wtrans_k(const float* __restrict__ Wq,
                                                const float* __restrict__ Wk,
                                                const float* __restrict__ Wv,
                                                _Float16* __restrict__ Wt) {
    int idx = blockIdx.x * 256 + threadIdx.x;   // 98304 = 3*512*64
    int p = idx >> 15, rem = idx & 32767;
    int k = rem >> 6;      // input row
    int n = rem & 63;      // input col (lane-fast -> coalesced read)
    const float* W = (p == 0) ? Wq : ((p == 1) ? Wk : Wv);
    int ctg = p * 4 + (n >> 4), m = n & 15;
    int kc = k >> 5, quad = (k >> 3) & 3, j = k & 7;
    Wt[(((ctg << 4) + kc) * 64 + (quad << 4) + m) * 8 + j] = (_Float16)W[k * 64 + n];
}

// ---------------- Kernel 1: QKV projection, 32-row blocks (r16 verbatim) ----
// grid 512 x 256 (4 waves). Block = TWO 16-row x-tiles staged to LDS in one
// batched coalesced burst; wave = 3 N-tiles; each W-chunk load feeds 2 MFMAs.
#define XS_STRIDE 536
__global__ __launch_bounds__(256) void proj_k(const float* __restrict__ x,
                                              const _Float16* __restrict__ Wt,
                                              const float* __restrict__ bq,
                                              const float* __restrict__ bk,
                                              const float* __restrict__ bv,
                                              _Float16* __restrict__ Qh,
                                              _Float16* __restrict__ Kh,
                                              _Float16* __restrict__ Vh) {
    __shared__ _Float16 xs[2][16 * XS_STRIDE];   // 34.3 KB

    int tid = threadIdx.x, l = tid & 63, wv = tid >> 6;
    int m = l & 15, quad = l >> 4;
    int row0 = blockIdx.x * 32;

#pragma unroll
    for (int s = 0; s < 2; s++)
#pragma unroll
        for (int i = 0; i < 8; i++) {
            int idx = tid + i * 256;
            int row = idx >> 7, c4 = idx & 127;
            float4 v = *(const float4*)(x + (row0 + s * 16 + row) * 512 + c4 * 4);
            union { half2v h[2]; uint2 u; } cv;
            cv.h[0][0] = (_Float16)v.x; cv.h[0][1] = (_Float16)v.y;
            cv.h[1][0] = (_Float16)v.z; cv.h[1][1] = (_Float16)v.w;
            *(uint2*)(xs[s] + row * XS_STRIDE + c4 * 4) = cv.u;
        }
    __syncthreads();

    const _Float16* arow0 = xs[0] + m * XS_STRIDE + quad * 8;
    const _Float16* arow1 = xs[1] + m * XS_STRIDE + quad * 8;

    floatx4 acc[2][3];
#pragma unroll
    for (int s = 0; s < 2; s++)
#pragma unroll
        for (int i = 0; i < 3; i++) acc[s][i] = (floatx4)(0.f);

#pragma unroll 4
    for (int kc = 0; kc < 16; kc++) {
        half8v a0 = *(const half8v*)(arow0 + kc * 32);
        half8v a1 = *(const half8v*)(arow1 + kc * 32);
#pragma unroll
        for (int ct = 0; ct < 3; ct++) {
            int ctg = wv * 3 + ct;
            half8v b = *(const half8v*)(Wt + (((ctg << 4) + kc) * 64 + l) * 8);
            acc[0][ct] = __builtin_amdgcn_mfma_f32_16x16x32_f16(a0, b, acc[0][ct], 0, 0, 0);
            acc[1][ct] = __builtin_amdgcn_mfma_f32_16x16x32_f16(a1, b, acc[1][ct], 0, 0, 0);
        }
    }

#pragma unroll
    for (int s = 0; s < 2; s++) {
        int rowb = row0 + s * 16;
#pragma unroll
        for (int ct = 0; ct < 3; ct++) {
            int ctg = wv * 3 + ct;
            int col = ctg * 16 + m;
            float bias = (ctg < 4) ? bq[col] : ((ctg < 8) ? bk[col - 64] : bv[col - 128]);
            if (ctg < 8) {
                _Float16* dst = (ctg < 4) ? Qh : Kh;
                float scl = (ctg < 4) ? LOG2E_OVER_8 : 1.0f;
                int dd = (ctg & 3) * 16 + m;
                int c = dd >> 5, quadQ = (dd >> 3) & 3, j = dd & 7;
#pragma unroll
                for (int r = 0; r < 4; r++) {
                    int row = rowb + quad * 4 + r;
                    int chunk = ((row >> 4) << 1) + c;
                    dst[(chunk * 64 + quadQ * 16 + (row & 15)) * 8 + j] =
                        (_Float16)((acc[s][ct][r] + bias) * scl);
                }
            } else {
                int dt = ctg - 8;
                int t64 = rowb >> 6, ktp = (rowb >> 5) & 1, half = (rowb >> 4) & 1;
                int chunk = t64 * 8 + dt * 2 + ktp;
                union { _Float16 h[4]; unsigned long long u; } pk;
#pragma unroll
                for (int r = 0; r < 4; r++) pk.h[r] = (_Float16)(acc[s][ct][r] + bias);
                *(unsigned long long*)(Vh + (chunk * 64 + quad * 16 + m) * 8 + half * 4) = pk.u;
            }
        }
    }
}

// ---------------- Kernel 2: attention (measured optimum: spl=8, grid 1024) --
// grid = qblk x ngrp (ngrp = 32; bid & 31 -> XCD-pinned K/V slice).
// Block: 4 independent waves (no __syncthreads), 32 q each, NT=8 64-key tiles.
// All frag loads 1 KB coalesced from frag-order Kh/Vh (L2-resident).
template <int NT>
__global__ __launch_bounds__(256) void attn_k(const _Float16* __restrict__ Qh,
                                              const _Float16* __restrict__ Kh,
                                              const _Float16* __restrict__ Vh,
                                              const int* __restrict__ mask,
                                              _Float16* __restrict__ Np,
                                              float* __restrict__ Dp,
                                              int gshift) {
    __shared__ float T[4][16 * 68];   // wave-private epilogue transpose (17.4 KB)

    int tid = threadIdx.x, l = tid & 63, wv = tid >> 6;
    int m = l & 15, quad = l >> 4;
    int bid = blockIdx.x;
    int grp = bid & ((1 << gshift) - 1), qblk = bid >> gshift;
    int os = grp >> 2, b = grp & 3;
    int q0 = qblk * 128 + wv * 32;

    const int* maskb = mask + b * 4096 + os * (NT * 64);
    int az = 0;
#pragma unroll
    for (int i = 0; i < NT; i++) az |= (maskb[l + i * 64] == 0);
    const bool hasz = __any(az);

    int qt_g = (b * 4096 + q0) >> 4;
    half8v qf[2][2];
#pragma unroll
    for (int qt = 0; qt < 2; qt++)
#pragma unroll
        for (int c = 0; c < 2; c++)
            qf[qt][c] = *(const half8v*)(Qh + (((qt_g + qt) * 2 + c) * 64 + l) * 8);

    int tb0 = (b * 64 + os * NT) * 512;   // uint4 idx of this slice's tile 0
    const uint4* kh4 = (const uint4*)Kh + tb0;
    const uint4* vh4 = (const uint4*)Vh + tb0;

    floatx4 oacc[2][4];
#pragma unroll
    for (int qt = 0; qt < 2; qt++)
#pragma unroll
        for (int dt = 0; dt < 4; dt++) oacc[qt][dt] = (floatx4)(0.f);
    float dl[2] = {0.f, 0.f};

#pragma unroll 2
    for (int t = 0; t < NT; t++) {
        const uint4* kt4 = kh4 + t * 512;
        const uint4* vt4 = vh4 + t * 512;
        uint4 vv[4];
#pragma unroll
        for (int sub = 0; sub < 4; sub++) {
            union { uint4 u; half8v h; } ku0, ku1;
            ku0.u = kt4[(sub * 2 + 0) * 64 + l];
            ku1.u = kt4[(sub * 2 + 1) * 64 + l];
            if ((sub & 1) == 0) {
#pragma unroll
                for (int dt = 0; dt < 4; dt++)
                    vv[dt] = vt4[(dt * 2 + (sub >> 1)) * 64 + l];
            }
            half4v pb[2];
#pragma unroll
            for (int qt = 0; qt < 2; qt++) {
                floatx4 sf = (floatx4)(0.f);
                sf = __builtin_amdgcn_mfma_f32_16x16x32_f16(ku0.h, qf[qt][0], sf, 0, 0, 0);
                sf = __builtin_amdgcn_mfma_f32_16x16x32_f16(ku1.h, qf[qt][1], sf, 0, 0, 0);
                float p0 = exp2f(sf[0]), p1 = exp2f(sf[1]);
                float p2 = exp2f(sf[2]), p3 = exp2f(sf[3]);
                dl[qt] += (p0 + p1) + (p2 + p3);
                if (hasz) {   // post-softmax -inf fill (rare path)
                    int kg = t * 64 + sub * 16 + quad * 4;
                    if (maskb[kg + 0] == 0) p0 = -__builtin_inff();
                    if (maskb[kg + 1] == 0) p1 = -__builtin_inff();
                    if (maskb[kg + 2] == 0) p2 = -__builtin_inff();
                    if (maskb[kg + 3] == 0) p3 = -__builtin_inff();
                }
                union { fp16x2 h[2]; half4v h4; } pu;
                pu.h[0] = __builtin_amdgcn_cvt_pkrtz(p0, p1);
                pu.h[1] = __builtin_amdgcn_cvt_pkrtz(p2, p3);
                pb[qt] = pu.h4;
            }
#pragma unroll
            for (int dt = 0; dt < 4; dt++) {
                union { uint4 u; half4v h[2]; } vc; vc.u = vv[dt];
                half4v va = vc.h[sub & 1];
                oacc[0][dt] = __builtin_amdgcn_mfma_f32_16x16x16f16(va, pb[0], oacc[0][dt], 0, 0, 0);
                oacc[1][dt] = __builtin_amdgcn_mfma_f32_16x16x16f16(va, pb[1], oacc[1][dt], 0, 0, 0);
            }
        }
    }

    // epilogue: den + O^T transpose via wave-private LDS (no barrier), fp16 out
    float* Tw = &T[wv][0];
    int rowb = os * 16384 + b * 4096 + q0;
#pragma unroll
    for (int qt = 0; qt < 2; qt++) {
        float dqt = dl[qt];
        dqt += __shfl_xor(dqt, 16, 64);
        dqt += __shfl_xor(dqt, 32, 64);
        if (l < 16) Dp[rowb + qt * 16 + l] = dqt;
#pragma unroll
        for (int dt = 0; dt < 4; dt++)
#pragma unroll
            for (int r = 0; r < 4; r++)
                Tw[m * 68 + dt * 16 + quad * 4 + r] = oacc[qt][dt][r];
        __builtin_amdgcn_s_waitcnt(0);   // wave-private LDS: lgkm drain only
#pragma unroll
        for (int g = 0; g < 4; g++) {
            int idx = g * 64 + l;
            int row = idx >> 4, c4 = (idx & 15) * 4;
            float4 v = *(const float4*)(Tw + row * 68 + c4);
            union { half4v h; unsigned long long u; } pk;
            pk.h[0] = (_Float16)v.x; pk.h[1] = (_Float16)v.y;
            pk.h[2] = (_Float16)v.z; pk.h[3] = (_Float16)v.w;
            *(unsigned long long*)(Np + (size_t)(rowb + qt * 16 + row) * 64 + c4) = pk.u;
        }
        __builtin_amdgcn_s_waitcnt(0);   // reads done before next qt overwrite
    }
}

// ---------------- Kernel 3: combine spl key-split partials (fp16 Np) --------
__global__ __launch_bounds__(256) void combine_k(const _Float16* __restrict__ Np,
                                                 const float* __restrict__ Dp,
                                                 float* __restrict__ out,
                                                 int spl) {
    int g4 = blockIdx.x * 256 + threadIdx.x;   // 262144 groups of 4 values
    int row = g4 >> 4;
    float4 nu = make_float4(0.f, 0.f, 0.f, 0.f);
    float d = 0.f;
    for (int sp = 0; sp < spl; sp++) {
        union { unsigned long long u; half4v h; } v;
        v.u = *(const unsigned long long*)(Np + ((size_t)sp << 20) + (size_t)g4 * 4);
        nu.x += (float)v.h[0]; nu.y += (float)v.h[1];
        nu.z += (float)v.h[2]; nu.w += (float)v.h[3];
        d += Dp[sp * 16384 + row];
    }
    float inv = 1.0f / d;
    ((float4*)out)[g4] = make_float4(nu.x * inv, nu.y * inv, nu.z * inv, nu.w * inv);
}

extern "C" void kernel_launch(void* const* d_in, const int* in_sizes, int n_in,
                              void* d_out, int out_size, void* d_ws, size_t ws_size,
                              hipStream_t stream) {
    const float* x  = (const float*)d_in[0];
    const int* mask = (const int*)d_in[1];
    const float* Wq = (const float*)d_in[2];
    const float* bq = (const float*)d_in[3];
    const float* Wk = (const float*)d_in[4];
    const float* bk = (const float*)d_in[5];
    const float* Wv = (const float*)d_in[6];
    const float* bv = (const float*)d_in[7];
    float* out = (float*)d_out;

    char* ws = (char*)d_ws;
    _Float16* Wt = (_Float16*)(ws);              // 192 KB frag-order
    _Float16* Qh = (_Float16*)(ws + 0x40000);    // 2 MB frag-order
    _Float16* Kh = (_Float16*)(ws + 0x240000);   // 2 MB frag-order
    _Float16* Vh = (_Float16*)(ws + 0x440000);   // 2 MB V^T frag-order
    float*    Dp = (float*)(ws + 0x640000);      // 512 KB [8][16384]
    _Float16* Np = (_Float16*)(ws + 0x740000);   // 8 * 2 MB fp16 partials

    // spl = 8: attn split-invariant at grid 1024 (r12/r13); combine halved vs 16
    wtrans_k<<<384, 256, 0, stream>>>(Wq, Wk, Wv, Wt);
    proj_k<<<512, 256, 0, stream>>>(x, Wt, bq, bk, bv, Qh, Kh, Vh);
    attn_k<8><<<32 * 32, 256, 0, stream>>>(Qh, Kh, Vh, mask, Np, Dp, 5);
    combine_k<<<1024, 256, 0, stream>>>(Np, Dp, out, 8);
}